// Round 2
// baseline (726.651 us; speedup 1.0000x reference)
//
#include <hip/hip_runtime.h>
#include <cstdint>
#include <cstddef>

// ---- fixed problem shape ----
constexpr int kB    = 4;
constexpr int kL    = 2048;
constexpr int kH    = 32;
constexpr int kP    = 64;
constexpr int kN    = 32;
constexpr int kD    = 2048;      // d_model
constexpr int kProjW = 4192;
constexpr int kLdp  = 4224;      // padded proj width (projh stride) = 33*128
constexpr int kNp1  = 4352;      // GEMM1 N padded to 17*256 (Wt rows only)
constexpr int kM    = kB * kL;   // 8192
constexpr int kK    = kD;        // 2048
constexpr int kLC   = 128;       // scan chunk length
constexpr int kNC   = kL / kLC;  // 16

typedef _Float16 f16x8 __attribute__((ext_vector_type(8)));
typedef float f32x4 __attribute__((ext_vector_type(4)));

__device__ __forceinline__ float lane_bcast(float v, int lane) {
    return __int_as_float(__builtin_amdgcn_readlane(__float_as_int(v), lane));
}
__device__ __forceinline__ float silu_f(float x) { return x / (1.f + __expf(-x)); }

__device__ __forceinline__ void async_copy16(const void* g, void* lds) {
    __builtin_amdgcn_global_load_lds(
        (const __attribute__((address_space(1))) unsigned int*)(uintptr_t)g,
        (__attribute__((address_space(3))) unsigned int*)(uintptr_t)lds,
        16, 0, 0);
}

// ---------------- cast fp32 -> fp16 (8 elems/thread) ----------------
__global__ __launch_bounds__(256) void cast_f16_kernel(const float* __restrict__ in,
                                                       _Float16* __restrict__ out) {
    size_t i = ((size_t)blockIdx.x * 256 + threadIdx.x) * 8;
    float4 a = *(const float4*)(in + i);
    float4 b = *(const float4*)(in + i + 4);
    f16x8 o;
    o[0] = (_Float16)a.x; o[1] = (_Float16)a.y; o[2] = (_Float16)a.z; o[3] = (_Float16)a.w;
    o[4] = (_Float16)b.x; o[5] = (_Float16)b.y; o[6] = (_Float16)b.z; o[7] = (_Float16)b.w;
    *(f16x8*)(out + i) = o;
}

// ------------- transpose + cast: W (R x C fp32) -> Wt (Cpad x R f16), zero pad -------------
__global__ __launch_bounds__(256) void transpose_cast_kernel(const float* __restrict__ W,
                                                             _Float16* __restrict__ Wt,
                                                             int R, int C) {
    __shared__ float tile[32][33];
    const int c0 = blockIdx.x * 32;
    const int r0 = blockIdx.y * 32;
    const int tx = threadIdx.x & 31;
    const int ty = threadIdx.x >> 5;   // 0..7
    #pragma unroll
    for (int i = 0; i < 32; i += 8) {
        int rr = r0 + ty + i;
        int cc = c0 + tx;
        tile[ty + i][tx] = (cc < C) ? W[(size_t)rr * C + cc] : 0.f;
    }
    __syncthreads();
    #pragma unroll
    for (int i = 0; i < 32; i += 8) {
        int cc = c0 + ty + i;          // row in Wt
        int rr = r0 + tx;              // col in Wt
        Wt[(size_t)cc * R + rr] = (_Float16)tile[tx][ty + i];
    }
}

// ---------------- GEMM: C[M x N] = A[M x K] * Bt[N x K]^T (+bias) ----------------
// 256x256 tile, BK=64, 512 threads (8 waves = 2M x 4N), 16x16x32 f16 MFMA.
// 4-phase K-tile, ONE barrier per phase, counted lgkm waits:
//   p1 Q(A0,B0): read B0+A0 (12, k0-group first); STAGE B0(kt+1)->buf^1;
//                lgkm(6) -> 8 MFMA(k0); lgkm(0) -> 8 MFMA(k1); barrier
//   p2 Q(A0,B1): read B1 (4); STAGE A0(kt+2)->buf; lgkm(2)/lgkm(0) clusters; barrier
//   p3 Q(A1,B1): read A1 (8); STAGE B1(kt+2)->buf; lgkm(4)/lgkm(0) clusters; barrier
//   p4 Q(A1,B0): register-only (B0 kept in bfr since p1); STAGE A1(kt+2)->buf;
//                16 MFMA; vmcnt(6) [0 on tail]; barrier
// k-outer MFMA clusters: dependent same-acc pairs are 8 apart (no back-to-back
// dependent MFMA issue stalls). sched_barrier(0) after each counted lgkm pins
// clusters below their wait (rule: compiler may hoist reg-only MFMA past asm).
// Race-safety (1 barrier/phase): each phase's reads retire at its own lgkm(0)
// before its closing barrier; each STAGE issues after that barrier and targets
// a slot last read >=1 phase earlier. Cross-wave staged-data visibility is
// guaranteed by vmcnt(N)-then-barrier at tile boundaries only (issue order
// A0,B1,A1 | B0 per tile is monotone -> vmcnt(6) retires exactly tile kt+1).
// LDS lane-linear layout (conflict-free): frag(grp g, kblk kk) byte offset =
// g*2048 + kk*1024 + lane*16 within the 16 KB half-tile part.
// XCD swizzle: bijective (nwg%8==0), each XCD owns a contiguous wg chunk.
template <bool OUT_F16>
__global__ __launch_bounds__(512, 2) void gemm256_kernel(
    const _Float16* __restrict__ A, const _Float16* __restrict__ Bt,
    const float* __restrict__ bias, int nbias,
    void* __restrict__ Cout, int K, int ldc, int nvalid, int nn,
    float* __restrict__ dtside)
{
    __shared__ __attribute__((aligned(16))) _Float16 lds[2 * 4 * 8192]; // 128 KiB

    const int tid = threadIdx.x;
    const int l = tid & 63, r = l & 15, q = l >> 4;
    const int w = tid >> 6, wm = w >> 2, wn = w & 3;

    // bijective XCD-aware swizzle: XCD x owns wg in [x*q8, (x+1)*q8)
    const int nwg = gridDim.x;
    const int q8 = nwg >> 3;
    const int pid = blockIdx.x;
    const int wg = (pid & 7) * q8 + (pid >> 3);
    const int m_idx = wg / nn;
    const int n_idx = wg - m_idx * nn;
    const size_t tileM = (size_t)m_idx * 256;
    const size_t tileN = (size_t)n_idx * 256;

    // staging source: thread t loads 16B from row sR (+64 for 2nd copy, +128
    // for half1), k-col sC; dest is lane-linear within the half-tile part.
    const int sR = ((tid >> 7) << 4) | (tid & 15);   // 0..63
    const int sC = ((tid >> 4) & 7) << 3;            // 0..56
    const _Float16* aSrc = A  + (tileM + sR) * (size_t)K + sC;
    const _Float16* bSrc = Bt + (tileN + sR) * (size_t)K + sC;
    _Float16* dst0 = lds + tid * 8;

    auto STAGE = [&](int buf, int part, const _Float16* src, int half, int kt2) {
        const _Float16* s = src + (size_t)(half * 128) * K + kt2 * 64;
        _Float16* d = dst0 + buf * 32768 + part * 8192;
        async_copy16(s, d);
        async_copy16(s + (size_t)64 * K, d + 4096);
    };

    const int NT = K >> 6;   // 32
    // prologue stream: A0(0),B1(0),A1(0),B0(0),A0(1),B1(1),A1(1)  (parts: A0=0,A1=1,B0=2,B1=3)
    STAGE(0, 0, aSrc, 0, 0); STAGE(0, 3, bSrc, 1, 0);
    STAGE(0, 1, aSrc, 1, 0); STAGE(0, 2, bSrc, 0, 0);
    STAGE(1, 0, aSrc, 0, 1); STAGE(1, 3, bSrc, 1, 1);
    STAGE(1, 1, aSrc, 1, 1);
    asm volatile("s_waitcnt vmcnt(6)" ::: "memory");   // K-tile 0 landed
    asm volatile("s_barrier" ::: "memory");

    f32x4 acc[8][4] = {};
    f16x8 afr[4][2], bfr[2][2], bfr2[2][2];

    const int aRd = wm * 4 * 2048 + l * 16;   // byte offset in A part (+i*2048 +kk*1024)
    const int bRd = wn * 2 * 2048 + l * 16;   // byte offset in B part (+j*2048 +kk*1024)

#define MFMA_CL(AO, BO, BARR, KK)                                                        \
    _Pragma("unroll")                                                                    \
    for (int i = 0; i < 4; ++i)                                                          \
        _Pragma("unroll")                                                                \
        for (int j = 0; j < 2; ++j)                                                      \
            acc[(AO) + i][(BO) + j] = __builtin_amdgcn_mfma_f32_16x16x32_f16(            \
                afr[i][KK], BARR[j][KK], acc[(AO) + i][(BO) + j], 0, 0, 0);

    for (int kt = 0; kt < NT; ++kt) {
        const int bsel = kt & 1;
        const char* a0 = (const char*)lds + bsel * 65536;
        const char* a1 = a0 + 16384;
        const char* b0 = a0 + 2 * 16384;
        const char* b1 = a0 + 3 * 16384;

        // ---- phase 1: Q(A0,B0) ----
        bfr[0][0] = *(const f16x8*)(b0 + bRd);
        bfr[1][0] = *(const f16x8*)(b0 + bRd + 2048);
        afr[0][0] = *(const f16x8*)(a0 + aRd);
        afr[1][0] = *(const f16x8*)(a0 + aRd + 2048);
        afr[2][0] = *(const f16x8*)(a0 + aRd + 4096);
        afr[3][0] = *(const f16x8*)(a0 + aRd + 6144);
        bfr[0][1] = *(const f16x8*)(b0 + bRd + 1024);
        bfr[1][1] = *(const f16x8*)(b0 + bRd + 3072);
        afr[0][1] = *(const f16x8*)(a0 + aRd + 1024);
        afr[1][1] = *(const f16x8*)(a0 + aRd + 3072);
        afr[2][1] = *(const f16x8*)(a0 + aRd + 5120);
        afr[3][1] = *(const f16x8*)(a0 + aRd + 7168);
        if (kt + 1 < NT) STAGE(bsel ^ 1, 2, bSrc, 0, kt + 1);   // B0(kt+1)
        asm volatile("s_waitcnt lgkmcnt(6)" ::: "memory");
        __builtin_amdgcn_sched_barrier(0);
        __builtin_amdgcn_s_setprio(1);
        MFMA_CL(0, 0, bfr, 0)
        asm volatile("s_waitcnt lgkmcnt(0)" ::: "memory");
        __builtin_amdgcn_sched_barrier(0);
        MFMA_CL(0, 0, bfr, 1)
        __builtin_amdgcn_s_setprio(0);
        asm volatile("s_barrier" ::: "memory");

        // ---- phase 2: Q(A0,B1) ----
        bfr2[0][0] = *(const f16x8*)(b1 + bRd);
        bfr2[1][0] = *(const f16x8*)(b1 + bRd + 2048);
        bfr2[0][1] = *(const f16x8*)(b1 + bRd + 1024);
        bfr2[1][1] = *(const f16x8*)(b1 + bRd + 3072);
        if (kt + 2 < NT) STAGE(bsel, 0, aSrc, 0, kt + 2);       // A0(kt+2)
        asm volatile("s_waitcnt lgkmcnt(2)" ::: "memory");
        __builtin_amdgcn_sched_barrier(0);
        __builtin_amdgcn_s_setprio(1);
        MFMA_CL(0, 2, bfr2, 0)
        asm volatile("s_waitcnt lgkmcnt(0)" ::: "memory");
        __builtin_amdgcn_sched_barrier(0);
        MFMA_CL(0, 2, bfr2, 1)
        __builtin_amdgcn_s_setprio(0);
        asm volatile("s_barrier" ::: "memory");

        // ---- phase 3: Q(A1,B1) ----
        afr[0][0] = *(const f16x8*)(a1 + aRd);
        afr[1][0] = *(const f16x8*)(a1 + aRd + 2048);
        afr[2][0] = *(const f16x8*)(a1 + aRd + 4096);
        afr[3][0] = *(const f16x8*)(a1 + aRd + 6144);
        afr[0][1] = *(const f16x8*)(a1 + aRd + 1024);
        afr[1][1] = *(const f16x8*)(a1 + aRd + 3072);
        afr[2][1] = *(const f16x8*)(a1 + aRd + 5120);
        afr[3][1] = *(const f16x8*)(a1 + aRd + 7168);
        if (kt + 2 < NT) STAGE(bsel, 3, bSrc, 1, kt + 2);       // B1(kt+2)
        asm volatile("s_waitcnt lgkmcnt(4)" ::: "memory");
        __builtin_amdgcn_sched_barrier(0);
        __builtin_amdgcn_s_setprio(1);
        MFMA_CL(4, 2, bfr2, 0)
        asm volatile("s_waitcnt lgkmcnt(0)" ::: "memory");
        __builtin_amdgcn_sched_barrier(0);
        MFMA_CL(4, 2, bfr2, 1)
        __builtin_amdgcn_s_setprio(0);
        asm volatile("s_barrier" ::: "memory");

        // ---- phase 4: Q(A1,B0) — register-only (B0 live in bfr since p1) ----
        if (kt + 2 < NT) STAGE(bsel, 1, aSrc, 1, kt + 2);       // A1(kt+2)
        __builtin_amdgcn_s_setprio(1);
        MFMA_CL(4, 0, bfr, 0)
        MFMA_CL(4, 0, bfr, 1)
        __builtin_amdgcn_s_setprio(0);
        if (kt + 2 < NT) asm volatile("s_waitcnt vmcnt(6)" ::: "memory");  // kt+1 confirmed
        else             asm volatile("s_waitcnt vmcnt(0)" ::: "memory");  // tail drain
        asm volatile("s_barrier" ::: "memory");
    }
#undef MFMA_CL

    // ---- epilogue: C/D layout col=lane&15, row=(lane>>4)*4+u ----
    #pragma unroll
    for (int bb = 0; bb < 4; ++bb) {
        const int nh = bb >> 1, j = bb & 1;
        const int col = (int)tileN + nh * 128 + wn * 32 + j * 16 + r;
        if (col >= nvalid) continue;
        float bv = 0.f;
        if (bias != nullptr && col < nbias) bv = bias[col];
        #pragma unroll
        for (int aa = 0; aa < 8; ++aa) {
            const int mh = aa >> 2, i = aa & 3;
            const size_t row = tileM + (size_t)(mh * 128 + wm * 64 + i * 16 + q * 4);
            #pragma unroll
            for (int u = 0; u < 4; ++u) {
                float v = acc[aa][bb][u] + bv;
                if (OUT_F16) ((_Float16*)Cout)[(row + u) * (size_t)ldc + col] = (_Float16)v;
                else         ((float*)Cout)[(row + u) * (size_t)ldc + col] = v;
                if (dtside != nullptr && col >= 4160 && col < 4192)
                    dtside[(row + u) * 32 + (col - 4160)] = v;
            }
        }
    }
}

// ---------------- dt / dA precompute ----------------
__global__ __launch_bounds__(256) void dt_da_kernel(
    const float* __restrict__ dtraw, const float* __restrict__ A_log,
    const float* __restrict__ dt_bias, float* __restrict__ dtv, float* __restrict__ dAv)
{
    int idx = blockIdx.x * 256 + threadIdx.x;  // (b,h,t) t-minor
    int t  = idx & (kL - 1);
    int bh = idx >> 11;
    int h  = bh & (kH - 1);
    int b  = bh >> 5;
    float z  = dtraw[((size_t)(b * kL + t)) * kH + h] + dt_bias[h];
    float dt = (z > 20.f) ? z : log1pf(expf(z));
    float dA = expf(dt * -expf(A_log[h]));
    dtv[idx] = dt;
    dAv[idx] = dA;
}

// ---------------- scan pass 1: per-chunk local states (zero init) + decay product --------
__global__ __launch_bounds__(64) void scan_pass1_kernel(
    const _Float16* __restrict__ projh, const float* __restrict__ conv_w,
    const float* __restrict__ conv_b, const float* __restrict__ dtv,
    const float* __restrict__ dAv, float* __restrict__ cstate, float* __restrict__ Pch)
{
    const int blk = blockIdx.x;
    const int c   = blk & (kNC - 1);
    const int bh  = blk >> 4;
    const int h   = bh & (kH - 1);
    const int b   = bh >> 5;
    const int l   = threadIdx.x;
    const int t0  = c * kLC;

    const int chx = h * kP + l;          // x conv channel
    const int chb = 2048 + (l & 31);     // B conv channel (duplicated over half-wave)
    const float xw0 = conv_w[chx*4+0], xw1 = conv_w[chx*4+1], xw2 = conv_w[chx*4+2], xw3 = conv_w[chx*4+3];
    const float xbb = conv_b[chx];
    const float bw0 = conv_w[chb*4+0], bw1 = conv_w[chb*4+1], bw2 = conv_w[chb*4+2], bw3 = conv_w[chb*4+3];
    const float bbb = conv_b[chb];

    const _Float16* pb = projh + (size_t)b * kL * kLdp;
    const int colx = 2048 + chx;
    const int colb = 2048 + chb;

    float xq0=0.f, xq1=0.f, xq2=0.f, bq0=0.f, bq1=0.f, bq2=0.f;
    if (c > 0) {
        xq0 = (float)pb[(size_t)(t0-3)*kLdp + colx];
        xq1 = (float)pb[(size_t)(t0-2)*kLdp + colx];
        xq2 = (float)pb[(size_t)(t0-1)*kLdp + colx];
        bq0 = (float)pb[(size_t)(t0-3)*kLdp + colb];
        bq1 = (float)pb[(size_t)(t0-2)*kLdp + colb];
        bq2 = (float)pb[(size_t)(t0-1)*kLdp + colb];
    }

    float hs[kN];
    #pragma unroll
    for (int n = 0; n < kN; ++n) hs[n] = 0.f;
    float Pp = 1.f;
    const float* dtp = dtv + (size_t)bh * kL;
    const float* dAp = dAv + (size_t)bh * kL;

    #pragma unroll 1
    for (int t = t0; t < t0 + kLC; ++t) {
        const size_t ro = (size_t)t * kLdp;
        float xv = (float)pb[ro + colx];
        float bv = (float)pb[ro + colb];
        float sx = silu_f(xbb + xw0*xq0 + xw1*xq1 + xw2*xq2 + xw3*xv);
        float sb = silu_f(bbb + bw0*bq0 + bw1*bq1 + bw2*bq2 + bw3*bv);
        xq0=xq1; xq1=xq2; xq2=xv;
        bq0=bq1; bq1=bq2; bq2=bv;
        float dt = dtp[t], dA = dAp[t];
        float dtx = dt * sx;
        Pp *= dA;
        #pragma unroll
        for (int n = 0; n < kN; ++n)
            hs[n] = fmaf(dA, hs[n], dtx * lane_bcast(sb, n));
    }
    float* cs = cstate + (size_t)blk * (kP * kN) + l * kN;
    #pragma unroll
    for (int n = 0; n < kN; ++n) cs[n] = hs[n];
    if (l == 0) Pch[blk] = Pp;
}

// ---------------- scan pass 2: sequential chunk combine (in place -> initial states) -----
__global__ __launch_bounds__(256) void scan_pass2_kernel(float* __restrict__ cstate,
                                                         const float* __restrict__ Pch) {
    const int bh  = blockIdx.x;
    const int off = threadIdx.x * 8;
    float s[8];
    #pragma unroll
    for (int i = 0; i < 8; ++i) s[i] = 0.f;
    float* base = cstate + (size_t)bh * (kNC * kP * kN) + off;
    #pragma unroll 1
    for (int c = 0; c < kNC; ++c) {
        float* cs = base + c * (kP * kN);
        float Pp = Pch[bh * kNC + c];
        #pragma unroll
        for (int i = 0; i < 8; ++i) {
            float loc = cs[i];
            cs[i] = s[i];                 // state entering chunk c
            s[i] = fmaf(Pp, s[i], loc);   // state entering chunk c+1
        }
    }
}

// ---------------- scan pass 3: replay chunk from known init state, emit y ----------------
__global__ __launch_bounds__(64) void scan_pass3_kernel(
    const _Float16* __restrict__ projh, const float* __restrict__ conv_w,
    const float* __restrict__ conv_b, const float* __restrict__ dtv,
    const float* __restrict__ dAv, const float* __restrict__ cstate,
    const float* __restrict__ D_param, float* __restrict__ ypre)
{
    const int blk = blockIdx.x;
    const int c   = blk & (kNC - 1);
    const int bh  = blk >> 4;
    const int h   = bh & (kH - 1);
    const int b   = bh >> 5;
    const int l   = threadIdx.x;
    const int t0  = c * kLC;

    const int chx = h * kP + l;      // x conv channel
    const int chc = 2048 + l;        // lanes 0..31 -> B channels, 32..63 -> C channels
    const float xw0 = conv_w[chx*4+0], xw1 = conv_w[chx*4+1], xw2 = conv_w[chx*4+2], xw3 = conv_w[chx*4+3];
    const float xbb = conv_b[chx];
    const float cw0 = conv_w[chc*4+0], cw1 = conv_w[chc*4+1], cw2 = conv_w[chc*4+2], cw3 = conv_w[chc*4+3];
    const float cbb = conv_b[chc];

    const _Float16* pb = projh + (size_t)b * kL * kLdp;
    const int colx = 2048 + chx;
    const int colc = 2048 + chc;     // = 4096 + l

    float xq0=0.f, xq1=0.f, xq2=0.f, cq0=0.f, cq1=0.f, cq2=0.f;
    if (c > 0) {
        xq0 = (float)pb[(size_t)(t0-3)*kLdp + colx];
        xq1 = (float)pb[(size_t)(t0-2)*kLdp + colx];
        xq2 = (float)pb[(size_t)(t0-1)*kLdp + colx];
        cq0 = (float)pb[(size_t)(t0-3)*kLdp + colc];
        cq1 = (float)pb[(size_t)(t0-2)*kLdp + colc];
        cq2 = (float)pb[(size_t)(t0-1)*kLdp + colc];
    }

    float hs[kN];
    const float* cs = cstate + (size_t)blk * (kP * kN) + l * kN;
    #pragma unroll
    for (int n = 0; n < kN; ++n) hs[n] = cs[n];
    const float Dh = D_param[h];
    const float* dtp = dtv + (size_t)bh * kL;
    const float* dAp = dAv + (size_t)bh * kL;
    float* yo = ypre + (size_t)b * kL * kD + h * kP + l;

    #pragma unroll 1
    for (int t = t0; t < t0 + kLC; ++t) {
        const size_t ro = (size_t)t * kLdp;
        float xv = (float)pb[ro + colx];
        float cv = (float)pb[ro + colc];
        float sx = silu_f(xbb + xw0*xq0 + xw1*xq1 + xw2*xq2 + xw3*xv);
        float sc = silu_f(cbb + cw0*cq0 + cw1*cq1 + cw2*cq2 + cw3*cv);
        xq0=xq1; xq1=xq2; xq2=xv;
        cq0=cq1; cq1=cq2; cq2=cv;
        float dt = dtp[t], dA = dAp[t];
        float dtx = dt * sx;
        float y0 = Dh * sx, y1 = 0.f;
        #pragma unroll
        for (int n = 0; n < kN; ++n) {
            float bn = lane_bcast(sc, n);
            float cn = lane_bcast(sc, n + 32);
            hs[n] = fmaf(dA, hs[n], dtx * bn);
            if (n & 1) y1 = fmaf(hs[n], cn, y1);
            else       y0 = fmaf(hs[n], cn, y0);
        }
        yo[(size_t)t * kD] = y0 + y1;
    }
}

// ---------------- gated RMSNorm -> f16 ----------------
__global__ __launch_bounds__(256) void gated_norm_kernel(
    const float* __restrict__ ypre, const _Float16* __restrict__ projh,
    const float* __restrict__ norm_w, _Float16* __restrict__ yh)
{
    const int row = blockIdx.x;
    const int tid = threadIdx.x;
    const float* yr = ypre + (size_t)row * kD;
    const _Float16* gr = projh + (size_t)row * kLdp;   // gate = cols [0,2048)
    float v[8];
    float ss = 0.f;
    #pragma unroll
    for (int u = 0; u < 8; ++u) {
        int col = tid + u * 256;
        float g = (float)gr[col];
        float t = yr[col] * (g / (1.f + __expf(-g)));
        v[u] = t;
        ss = fmaf(t, t, ss);
    }
    #pragma unroll
    for (int off = 32; off > 0; off >>= 1) ss += __shfl_xor(ss, off, 64);
    __shared__ float red[4];
    if ((tid & 63) == 0) red[tid >> 6] = ss;
    __syncthreads();
    float tot = (red[0] + red[1]) + (red[2] + red[3]);
    float scl = rsqrtf(tot * (1.f / (float)kD) + 1e-6f);
    #pragma unroll
    for (int u = 0; u < 8; ++u) {
        int col = tid + u * 256;
        yh[(size_t)row * kD + col] = (_Float16)(v[u] * scl * norm_w[col]);
    }
}

// ---------------- launcher ----------------
extern "C" void kernel_launch(void* const* d_in, const int* in_sizes, int n_in,
                              void* d_out, int out_size, void* d_ws, size_t ws_size,
                              hipStream_t stream)
{
    (void)in_sizes; (void)n_in; (void)out_size; (void)ws_size;
    const float* x       = (const float*)d_in[0];
    const float* W_in    = (const float*)d_in[1];
    const float* b_in    = (const float*)d_in[2];
    const float* conv_w  = (const float*)d_in[3];
    const float* conv_b  = (const float*)d_in[4];
    const float* A_log   = (const float*)d_in[5];
    const float* dt_bias = (const float*)d_in[6];
    const float* D_param = (const float*)d_in[7];
    const float* norm_w  = (const float*)d_in[8];
    const float* W_out   = (const float*)d_in[9];
    float* out = (float*)d_out;

    char* p = (char*)d_ws;
    _Float16* projh = (_Float16*)p; p += (size_t)kM * kLdp * 2;     // 69.2 MB
    _Float16* xh    = (_Float16*)p; p += (size_t)kM * kD * 2;       // 33.6 MB (reused as yh)
    _Float16* Wt    = (_Float16*)p; p += (size_t)kNp1 * kK * 2;     // 17.8 MB (N padded to 4352)
    _Float16* Wot   = (_Float16*)p; p += (size_t)kD * kK * 2;       //  8.4 MB
    float* dtraw    = (float*)p;    p += (size_t)kM * kH * 4;       //  1.0 MB
    float* dtv      = (float*)p;    p += (size_t)kB * kH * kL * 4;  //  1.0 MB
    float* dAv      = (float*)p;    p += (size_t)kB * kH * kL * 4;  //  1.0 MB
    float* cstate   = (float*)p;    p += (size_t)kB * kH * kNC * kP * kN * 4; // 16.8 MB
    float* Pch      = (float*)p;    p += (size_t)kB * kH * kNC * 4;
    _Float16* yh = xh;            // xh dead after GEMM1
    float* ypre = out;            // d_out used as fp32 scratch, overwritten by GEMM2

    // 1. cast x -> f16
    cast_f16_kernel<<<(kM * kD) / (256 * 8), 256, 0, stream>>>(x, xh);
    // 2-3. transpose+cast weights to N x K (pad W_in cols 4192->4352 with zeros)
    transpose_cast_kernel<<<dim3(kNp1 / 32, kK / 32), 256, 0, stream>>>(W_in, Wt, kK, kProjW);
    transpose_cast_kernel<<<dim3(kD / 32, kK / 32), 256, 0, stream>>>(W_out, Wot, kK, kD);
    // 4. GEMM1: proj = x @ W_in + b_in (256x256 tiles, 4-phase/1-barrier, 17 n-tiles)
    gemm256_kernel<true><<<(kM / 256) * (kNp1 / 256), 512, 0, stream>>>(
        xh, Wt, b_in, kProjW, (void*)projh, kK, kLdp, kLdp, kNp1 / 256, dtraw);
    // 5. dt / dA
    dt_da_kernel<<<(kB * kH * kL) / 256, 256, 0, stream>>>(dtraw, A_log, dt_bias, dtv, dAv);
    // 6-8. chunked scan (conv fused)
    scan_pass1_kernel<<<kB * kH * kNC, 64, 0, stream>>>(projh, conv_w, conv_b, dtv, dAv, cstate, Pch);
    scan_pass2_kernel<<<kB * kH, 256, 0, stream>>>(cstate, Pch);
    scan_pass3_kernel<<<kB * kH * kNC, 64, 0, stream>>>(projh, conv_w, conv_b, dtv, dAv, cstate, D_param, ypre);
    // 9. gated RMSNorm -> f16
    gated_norm_kernel<<<kM, 256, 0, stream>>>(ypre, projh, norm_w, yh);
    // 10. GEMM2: out = y @ W_out (256x256 tiles, 8 n-tiles, exactly 256 blocks)
    gemm256_kernel<false><<<(kM / 256) * (kD / 256), 512, 0, stream>>>(
        yh, Wot, nullptr, 0, (void*)out, kK, kD, kD, kD / 256, nullptr);
}

// Round 3
// 620.190 us; speedup vs baseline: 1.1717x; 1.1717x over previous
//
#include <hip/hip_runtime.h>
#include <cstdint>
#include <cstddef>

// ---- fixed problem shape ----
constexpr int kB    = 4;
constexpr int kL    = 2048;
constexpr int kH    = 32;
constexpr int kP    = 64;
constexpr int kN    = 32;
constexpr int kD    = 2048;      // d_model
constexpr int kProjW = 4192;
constexpr int kLdp  = 4224;      // padded proj width (projh stride) = 33*128
constexpr int kM    = kB * kL;   // 8192
constexpr int kK    = kD;        // 2048
constexpr int kLC   = 64;        // scan chunk length
constexpr int kNC   = kL / kLC;  // 32

typedef _Float16 f16x8 __attribute__((ext_vector_type(8)));
typedef float f32x4 __attribute__((ext_vector_type(4)));

__device__ __forceinline__ float lane_bcast(float v, int lane) {
    return __int_as_float(__builtin_amdgcn_readlane(__float_as_int(v), lane));
}
__device__ __forceinline__ float silu_f(float x) { return x / (1.f + __expf(-x)); }

__device__ __forceinline__ void async_copy16(const void* g, void* lds) {
    __builtin_amdgcn_global_load_lds(
        (const __attribute__((address_space(1))) unsigned int*)(uintptr_t)g,
        (__attribute__((address_space(3))) unsigned int*)(uintptr_t)lds,
        16, 0, 0);
}

// ---------------- cast fp32 -> fp16 (8 elems/thread) ----------------
__global__ __launch_bounds__(256) void cast_f16_kernel(const float* __restrict__ in,
                                                       _Float16* __restrict__ out) {
    size_t i = ((size_t)blockIdx.x * 256 + threadIdx.x) * 8;
    float4 a = *(const float4*)(in + i);
    float4 b = *(const float4*)(in + i + 4);
    f16x8 o;
    o[0] = (_Float16)a.x; o[1] = (_Float16)a.y; o[2] = (_Float16)a.z; o[3] = (_Float16)a.w;
    o[4] = (_Float16)b.x; o[5] = (_Float16)b.y; o[6] = (_Float16)b.z; o[7] = (_Float16)b.w;
    *(f16x8*)(out + i) = o;
}

// ------------- transpose + cast: W (R x C fp32) -> Wt (Cpad x R f16), zero pad -------------
__global__ __launch_bounds__(256) void transpose_cast_kernel(const float* __restrict__ W,
                                                             _Float16* __restrict__ Wt,
                                                             int R, int C) {
    __shared__ float tile[32][33];
    const int c0 = blockIdx.x * 32;
    const int r0 = blockIdx.y * 32;
    const int tx = threadIdx.x & 31;
    const int ty = threadIdx.x >> 5;   // 0..7
    #pragma unroll
    for (int i = 0; i < 32; i += 8) {
        int rr = r0 + ty + i;
        int cc = c0 + tx;
        tile[ty + i][tx] = (cc < C) ? W[(size_t)rr * C + cc] : 0.f;
    }
    __syncthreads();
    #pragma unroll
    for (int i = 0; i < 32; i += 8) {
        int cc = c0 + ty + i;          // row in Wt
        int rr = r0 + tx;              // col in Wt
        Wt[(size_t)cc * R + rr] = (_Float16)tile[tx][ty + i];
    }
}

// ---------------- GEMM: C[M x N] = A[M x K] * Bt[N x K]^T (+bias) ----------------
// 256x256 tile, BK=64, 512 threads (8 waves = 2M x 4N), 16x16x32 f16 MFMA.
// TWO barriers per K-tile with cross-phase prefetch:
//   tile start: read A0(8)+B0(4) [sched-fenced first], then B1(4);
//               STAGE B0(kt+1),A1(kt+1) -> buf^1;
//               lgkm(4) -> 16 MFMA Q(A0,B0); lgkm(0) -> 16 MFMA Q(A0,B1)
//   then: issue A1 reads(8) (their latency hides under barrier#1 sync);
//         barrier#1; STAGE A0(kt+2),B1(kt+2) -> buf;
//         lgkm(0) -> 32 MFMA Q(A1,B1)+Q(A1,B0) (B0 frags live since start);
//         vmcnt(4) [0 at tail]; barrier#2.
// Race-safety: A0/B0 reads retire at lgkm(4), B1 at lgkm(0)-pre-Q01 — all
// before barrier#1, so staging A0/B1(kt+2) into the CURRENT buf after
// barrier#1 is safe; pending A1 reads at barrier#1 target part1 (not staged
// there). B0/A1(kt+1) go to buf^1 whose readers retired last tile. FIFO
// accounting: outstanding groups after stages = [A0B1(kt+1)][B0A1(kt+1)]
// [A0B1(kt+2)] -> vmcnt(4) retires all of kt+1 exactly.
// LDS lane-linear layout (conflict-free): frag(grp g, kk) byte offset =
// g*2048 + kk*1024 + lane*16 within the 16 KB half-tile part.
// XCD swizzle: bijective (nwg%8==0), each XCD owns a contiguous wg chunk.
template <bool OUT_F16>
__global__ __launch_bounds__(512, 2) void gemm256_kernel(
    const _Float16* __restrict__ A, const _Float16* __restrict__ Bt,
    const float* __restrict__ bias, int nbias,
    void* __restrict__ Cout, int K, int ldc, int nvalid, int nn)
{
    __shared__ __attribute__((aligned(16))) _Float16 lds[2 * 4 * 8192]; // 128 KiB

    const int tid = threadIdx.x;
    const int l = tid & 63, r = l & 15, q = l >> 4;
    const int w = tid >> 6, wm = w >> 2, wn = w & 3;

    // bijective XCD-aware swizzle: XCD x owns wg in [x*q8, (x+1)*q8)
    const int nwg = gridDim.x;
    const int q8 = nwg >> 3;
    const int pid = blockIdx.x;
    const int wg = (pid & 7) * q8 + (pid >> 3);
    const int m_idx = wg / nn;
    const int n_idx = wg - m_idx * nn;
    const size_t tileM = (size_t)m_idx * 256;
    const size_t tileN = (size_t)n_idx * 256;

    // staging source: thread t loads 16B from row sR (+64 for 2nd copy, +128
    // for half1), k-col sC; dest is lane-linear within the half-tile part.
    const int sR = ((tid >> 7) << 4) | (tid & 15);   // 0..63
    const int sC = ((tid >> 4) & 7) << 3;            // 0..56
    const _Float16* aSrc = A  + (tileM + sR) * (size_t)K + sC;
    const _Float16* bSrc = Bt + (tileN + sR) * (size_t)K + sC;
    _Float16* dst0 = lds + tid * 8;

    auto STAGE = [&](int buf, int part, const _Float16* src, int half, int kt2) {
        const _Float16* s = src + (size_t)(half * 128) * K + kt2 * 64;
        _Float16* d = dst0 + buf * 32768 + part * 8192;
        async_copy16(s, d);
        async_copy16(s + (size_t)64 * K, d + 4096);
    };

    const int NT = K >> 5 >> 1;   // K/64
    // prologue: tile0 all parts (8 loads), then A0,B1 of tile1 (4 loads)
    STAGE(0, 0, aSrc, 0, 0); STAGE(0, 1, aSrc, 1, 0);
    STAGE(0, 2, bSrc, 0, 0); STAGE(0, 3, bSrc, 1, 0);
    STAGE(1, 0, aSrc, 0, 1); STAGE(1, 3, bSrc, 1, 1);
    asm volatile("s_waitcnt vmcnt(4)" ::: "memory");   // tile0 landed
    asm volatile("s_barrier" ::: "memory");

    f32x4 acc[8][4] = {};
    f16x8 afr[4][2], bfr[2][2], bfr2[2][2];

    const int aRd = wm * 4 * 2048 + l * 16;   // byte offset in A part (+i*2048 +kk*1024)
    const int bRd = wn * 2 * 2048 + l * 16;   // byte offset in B part (+j*2048 +kk*1024)

#define MFMA_CL(AO, BO, BARR, KK)                                                        \
    _Pragma("unroll")                                                                    \
    for (int i = 0; i < 4; ++i)                                                          \
        _Pragma("unroll")                                                                \
        for (int j = 0; j < 2; ++j)                                                      \
            acc[(AO) + i][(BO) + j] = __builtin_amdgcn_mfma_f32_16x16x32_f16(            \
                afr[i][KK], BARR[j][KK], acc[(AO) + i][(BO) + j], 0, 0, 0);

    for (int kt = 0; kt < NT; ++kt) {
        const int bsel = kt & 1;
        const char* a0p = (const char*)lds + bsel * 65536;
        const char* a1p = a0p + 16384;
        const char* b0p = a0p + 2 * 16384;
        const char* b1p = a0p + 3 * 16384;

        // tile-start reads: A0(8)+B0(4) first (fenced), then B1(4)
        afr[0][0] = *(const f16x8*)(a0p + aRd);
        afr[1][0] = *(const f16x8*)(a0p + aRd + 2048);
        afr[2][0] = *(const f16x8*)(a0p + aRd + 4096);
        afr[3][0] = *(const f16x8*)(a0p + aRd + 6144);
        afr[0][1] = *(const f16x8*)(a0p + aRd + 1024);
        afr[1][1] = *(const f16x8*)(a0p + aRd + 3072);
        afr[2][1] = *(const f16x8*)(a0p + aRd + 5120);
        afr[3][1] = *(const f16x8*)(a0p + aRd + 7168);
        bfr[0][0] = *(const f16x8*)(b0p + bRd);
        bfr[1][0] = *(const f16x8*)(b0p + bRd + 2048);
        bfr[0][1] = *(const f16x8*)(b0p + bRd + 1024);
        bfr[1][1] = *(const f16x8*)(b0p + bRd + 3072);
        __builtin_amdgcn_sched_barrier(0);   // keep A0+B0 as the oldest 12 lgkm ops
        bfr2[0][0] = *(const f16x8*)(b1p + bRd);
        bfr2[1][0] = *(const f16x8*)(b1p + bRd + 2048);
        bfr2[0][1] = *(const f16x8*)(b1p + bRd + 1024);
        bfr2[1][1] = *(const f16x8*)(b1p + bRd + 3072);
        if (kt + 1 < NT) {
            STAGE(bsel ^ 1, 2, bSrc, 0, kt + 1);   // B0(kt+1)
            STAGE(bsel ^ 1, 1, aSrc, 1, kt + 1);   // A1(kt+1)
        }
        asm volatile("s_waitcnt lgkmcnt(4)" ::: "memory");   // A0+B0 ready
        __builtin_amdgcn_sched_barrier(0);
        __builtin_amdgcn_s_setprio(1);
        MFMA_CL(0, 0, bfr, 0)
        MFMA_CL(0, 0, bfr, 1)
        asm volatile("s_waitcnt lgkmcnt(0)" ::: "memory");   // B1 ready
        __builtin_amdgcn_sched_barrier(0);
        MFMA_CL(0, 2, bfr2, 0)
        MFMA_CL(0, 2, bfr2, 1)
        __builtin_amdgcn_s_setprio(0);

        // A1 reads (A0 frags dead); latency hides under barrier#1 sync
        afr[0][0] = *(const f16x8*)(a1p + aRd);
        afr[1][0] = *(const f16x8*)(a1p + aRd + 2048);
        afr[2][0] = *(const f16x8*)(a1p + aRd + 4096);
        afr[3][0] = *(const f16x8*)(a1p + aRd + 6144);
        afr[0][1] = *(const f16x8*)(a1p + aRd + 1024);
        afr[1][1] = *(const f16x8*)(a1p + aRd + 3072);
        afr[2][1] = *(const f16x8*)(a1p + aRd + 5120);
        afr[3][1] = *(const f16x8*)(a1p + aRd + 7168);
        asm volatile("s_barrier" ::: "memory");              // barrier#1
        if (kt + 2 < NT) {
            STAGE(bsel, 0, aSrc, 0, kt + 2);   // A0(kt+2) (readers retired @ lgkm(4))
            STAGE(bsel, 3, bSrc, 1, kt + 2);   // B1(kt+2) (readers retired @ lgkm(0))
        }
        asm volatile("s_waitcnt lgkmcnt(0)" ::: "memory");   // A1 ready
        __builtin_amdgcn_sched_barrier(0);
        __builtin_amdgcn_s_setprio(1);
        MFMA_CL(4, 2, bfr2, 0)
        MFMA_CL(4, 2, bfr2, 1)
        MFMA_CL(4, 0, bfr, 0)
        MFMA_CL(4, 0, bfr, 1)
        __builtin_amdgcn_s_setprio(0);
        if (kt + 2 < NT) asm volatile("s_waitcnt vmcnt(4)" ::: "memory");  // all kt+1 landed
        else             asm volatile("s_waitcnt vmcnt(0)" ::: "memory");  // tail drain
        asm volatile("s_barrier" ::: "memory");              // barrier#2 (boundary)
    }
#undef MFMA_CL

    // ---- epilogue: C/D layout col=lane&15, row=(lane>>4)*4+u ----
    #pragma unroll
    for (int bb = 0; bb < 4; ++bb) {
        const int nh = bb >> 1, j = bb & 1;
        const int col = (int)tileN + nh * 128 + wn * 32 + j * 16 + r;
        if (col >= nvalid) continue;
        float bv = 0.f;
        if (bias != nullptr && col < nbias) bv = bias[col];
        #pragma unroll
        for (int aa = 0; aa < 8; ++aa) {
            const int mh = aa >> 2, i = aa & 3;
            const size_t row = tileM + (size_t)(mh * 128 + wm * 64 + i * 16 + q * 4);
            #pragma unroll
            for (int u = 0; u < 4; ++u) {
                float v = acc[aa][bb][u] + bv;
                if (OUT_F16) ((_Float16*)Cout)[(row + u) * (size_t)ldc + col] = (_Float16)v;
                else         ((float*)Cout)[(row + u) * (size_t)ldc + col] = v;
            }
        }
    }
}

// ------------- skinny GEMM tail: cols [4096,4224) of proj, + dt/dA fused -------------
// C[M x 128] = A[M x K] * Bt[128 x K]^T + bias. Tile 32x128, 256 blocks,
// 256 threads (4 waves, wave w owns cols w*32..w*32+31). Double-buffered LDS
// (A 4KB + B 16KB per buf), stage 2 tiles ahead, 2 barriers/tile.
// dt cols (offset 64..95): epilogue computes softplus/exp -> dtv/dAv directly.
__global__ __launch_bounds__(256) void gemm_tail_kernel(
    const _Float16* __restrict__ A, const _Float16* __restrict__ Bt,
    const float* __restrict__ bias /*96 valid*/, _Float16* __restrict__ Cout,
    const float* __restrict__ A_log, const float* __restrict__ dt_bias,
    float* __restrict__ dtv, float* __restrict__ dAv)
{
    __shared__ __attribute__((aligned(16))) _Float16 lds[2 * 10240]; // 40 KiB
    const int K = kK;
    const int tid = threadIdx.x;
    const int l = tid & 63, r = l & 15, q = l >> 4;
    const int w = tid >> 6;
    const size_t tileM = (size_t)blockIdx.x * 32;

    const int sRa = ((tid >> 7) << 4) | (tid & 15);   // 0..31
    const int sC  = ((tid >> 4) & 7) << 3;
    const _Float16* aSrc = A + (tileM + sRa) * (size_t)K + sC;
    const _Float16* bSrc = Bt + (size_t)sRa * K + sC;
    _Float16* dst0 = lds + tid * 8;

    auto STG = [&](int buf, int kt2) {
        const _Float16* a = aSrc + kt2 * 64;
        const _Float16* b = bSrc + kt2 * 64;
        _Float16* d = dst0 + buf * 10240;
        async_copy16(a, d);                                    // A part (4 KB)
        #pragma unroll
        for (int c = 0; c < 4; ++c)
            async_copy16(b + (size_t)(c * 32) * K, d + 2048 + c * 2048);  // B part (16 KB)
    };

    const int NT = K / 64;   // 32
    STG(0, 0); STG(1, 1);
    asm volatile("s_waitcnt vmcnt(5)" ::: "memory");
    asm volatile("s_barrier" ::: "memory");

    f32x4 acc[2][2] = {};
    f16x8 af[2][2], bf[2][2];
    const int aRdT = l * 16;
    const int bRdT = 4096 + w * 2 * 2048 + l * 16;

    for (int kt = 0; kt < NT; ++kt) {
        const char* base = (const char*)lds + (kt & 1) * 20480;
        af[0][0] = *(const f16x8*)(base + aRdT);
        af[1][0] = *(const f16x8*)(base + aRdT + 2048);
        af[0][1] = *(const f16x8*)(base + aRdT + 1024);
        af[1][1] = *(const f16x8*)(base + aRdT + 3072);
        bf[0][0] = *(const f16x8*)(base + bRdT);
        bf[1][0] = *(const f16x8*)(base + bRdT + 2048);
        bf[0][1] = *(const f16x8*)(base + bRdT + 1024);
        bf[1][1] = *(const f16x8*)(base + bRdT + 3072);
        asm volatile("s_waitcnt lgkmcnt(0)" ::: "memory");
        __builtin_amdgcn_sched_barrier(0);
        asm volatile("s_barrier" ::: "memory");     // all waves' reads done
        if (kt + 2 < NT) STG(kt & 1, kt + 2);
        #pragma unroll
        for (int kk = 0; kk < 2; ++kk)
            #pragma unroll
            for (int i = 0; i < 2; ++i)
                #pragma unroll
                for (int j = 0; j < 2; ++j)
                    acc[i][j] = __builtin_amdgcn_mfma_f32_16x16x32_f16(af[i][kk], bf[j][kk], acc[i][j], 0, 0, 0);
        if (kt + 2 < NT) asm volatile("s_waitcnt vmcnt(5)" ::: "memory");
        else             asm volatile("s_waitcnt vmcnt(0)" ::: "memory");
        asm volatile("s_barrier" ::: "memory");
    }

    // epilogue: col offset = w*32 + j*16 + r in [0,128); dt block = [64,96)
    #pragma unroll
    for (int j = 0; j < 2; ++j) {
        const int colOff = w * 32 + j * 16 + r;
        const float bv = (colOff < 96) ? bias[colOff] : 0.f;
        #pragma unroll
        for (int i = 0; i < 2; ++i) {
            #pragma unroll
            for (int u = 0; u < 4; ++u) {
                const size_t row = tileM + (size_t)(i * 16 + q * 4 + u);
                float v = acc[i][j][u] + bv;
                Cout[row * kLdp + 4096 + colOff] = (_Float16)v;
            }
        }
        if (colOff >= 64 && colOff < 96) {
            const int h = colOff - 64;
            const float db = dt_bias[h];
            const float nA = -expf(A_log[h]);
            #pragma unroll
            for (int i = 0; i < 2; ++i) {
                #pragma unroll
                for (int u = 0; u < 4; ++u) {
                    const size_t row = tileM + (size_t)(i * 16 + q * 4 + u);
                    const int b = (int)(row >> 11), t = (int)(row & 2047);
                    float z = acc[i][j][u] + bv + db;
                    float dt = (z > 20.f) ? z : log1pf(expf(z));
                    float dA = expf(dt * nA);
                    const size_t idx = (((size_t)b * kH + h) << 11) | t;
                    dtv[idx] = dt;
                    dAv[idx] = dA;
                }
            }
        }
    }
}

// ---------------- scan pass 1: per-chunk local states (zero init) + decay product --------
__global__ __launch_bounds__(64) void scan_pass1_kernel(
    const _Float16* __restrict__ projh, const float* __restrict__ conv_w,
    const float* __restrict__ conv_b, const float* __restrict__ dtv,
    const float* __restrict__ dAv, float* __restrict__ cstate, float* __restrict__ Pch)
{
    const int blk = blockIdx.x;
    const int c   = blk & (kNC - 1);
    const int bh  = blk >> 5;            // kNC = 32
    const int h   = bh & (kH - 1);
    const int b   = bh >> 5;
    const int l   = threadIdx.x;
    const int t0  = c * kLC;

    const int chx = h * kP + l;          // x conv channel
    const int chb = 2048 + (l & 31);     // B conv channel (duplicated over half-wave)
    const float xw0 = conv_w[chx*4+0], xw1 = conv_w[chx*4+1], xw2 = conv_w[chx*4+2], xw3 = conv_w[chx*4+3];
    const float xbb = conv_b[chx];
    const float bw0 = conv_w[chb*4+0], bw1 = conv_w[chb*4+1], bw2 = conv_w[chb*4+2], bw3 = conv_w[chb*4+3];
    const float bbb = conv_b[chb];

    const _Float16* pb = projh + (size_t)b * kL * kLdp;
    const int colx = 2048 + chx;
    const int colb = 2048 + chb;

    float xq0=0.f, xq1=0.f, xq2=0.f, bq0=0.f, bq1=0.f, bq2=0.f;
    if (c > 0) {
        xq0 = (float)pb[(size_t)(t0-3)*kLdp + colx];
        xq1 = (float)pb[(size_t)(t0-2)*kLdp + colx];
        xq2 = (float)pb[(size_t)(t0-1)*kLdp + colx];
        bq0 = (float)pb[(size_t)(t0-3)*kLdp + colb];
        bq1 = (float)pb[(size_t)(t0-2)*kLdp + colb];
        bq2 = (float)pb[(size_t)(t0-1)*kLdp + colb];
    }

    float hs[kN];
    #pragma unroll
    for (int n = 0; n < kN; ++n) hs[n] = 0.f;
    float Pp = 1.f;
    const float* dtp = dtv + (size_t)bh * kL;
    const float* dAp = dAv + (size_t)bh * kL;

    // rolling prefetch: values for t loaded one iteration ahead
    float xv = (float)pb[(size_t)t0 * kLdp + colx];
    float bv = (float)pb[(size_t)t0 * kLdp + colb];
    float dt = dtp[t0], dA = dAp[t0];

    #pragma unroll 1
    for (int t = t0; t < t0 + kLC; ++t) {
        float xn = 0.f, bn = 0.f, dtn = 0.f, dAn = 0.f;
        if (t + 1 < t0 + kLC) {
            const size_t ro2 = (size_t)(t + 1) * kLdp;
            xn = (float)pb[ro2 + colx];
            bn = (float)pb[ro2 + colb];
            dtn = dtp[t + 1]; dAn = dAp[t + 1];
        }
        float sx = silu_f(xbb + xw0*xq0 + xw1*xq1 + xw2*xq2 + xw3*xv);
        float sb = silu_f(bbb + bw0*bq0 + bw1*bq1 + bw2*bq2 + bw3*bv);
        xq0=xq1; xq1=xq2; xq2=xv;
        bq0=bq1; bq1=bq2; bq2=bv;
        float dtx = dt * sx;
        Pp *= dA;
        #pragma unroll
        for (int n = 0; n < kN; ++n)
            hs[n] = fmaf(dA, hs[n], dtx * lane_bcast(sb, n));
        xv = xn; bv = bn; dt = dtn; dA = dAn;
    }
    float* cs = cstate + (size_t)blk * (kP * kN) + l * kN;
    #pragma unroll
    for (int n = 0; n < kN; ++n) cs[n] = hs[n];
    if (l == 0) Pch[blk] = Pp;
}

// ---------------- scan pass 2: sequential chunk combine (in place -> initial states) -----
__global__ __launch_bounds__(256) void scan_pass2_kernel(float* __restrict__ cstate,
                                                         const float* __restrict__ Pch) {
    const int bh  = blockIdx.x;
    const int off = threadIdx.x * 8;
    float s[8];
    #pragma unroll
    for (int i = 0; i < 8; ++i) s[i] = 0.f;
    float* base = cstate + (size_t)bh * (kNC * kP * kN) + off;
    #pragma unroll 1
    for (int c = 0; c < kNC; ++c) {
        float* cs = base + c * (kP * kN);
        float Pp = Pch[bh * kNC + c];
        #pragma unroll
        for (int i = 0; i < 8; ++i) {
            float loc = cs[i];
            cs[i] = s[i];                 // state entering chunk c
            s[i] = fmaf(Pp, s[i], loc);   // state entering chunk c+1
        }
    }
}

// ---------------- scan pass 3: replay chunk from known init state, emit y ----------------
__global__ __launch_bounds__(64) void scan_pass3_kernel(
    const _Float16* __restrict__ projh, const float* __restrict__ conv_w,
    const float* __restrict__ conv_b, const float* __restrict__ dtv,
    const float* __restrict__ dAv, const float* __restrict__ cstate,
    const float* __restrict__ D_param, float* __restrict__ ypre)
{
    const int blk = blockIdx.x;
    const int c   = blk & (kNC - 1);
    const int bh  = blk >> 5;
    const int h   = bh & (kH - 1);
    const int b   = bh >> 5;
    const int l   = threadIdx.x;
    const int t0  = c * kLC;

    const int chx = h * kP + l;      // x conv channel
    const int chc = 2048 + l;        // lanes 0..31 -> B channels, 32..63 -> C channels
    const float xw0 = conv_w[chx*4+0], xw1 = conv_w[chx*4+1], xw2 = conv_w[chx*4+2], xw3 = conv_w[chx*4+3];
    const float xbb = conv_b[chx];
    const float cw0 = conv_w[chc*4+0], cw1 = conv_w[chc*4+1], cw2 = conv_w[chc*4+2], cw3 = conv_w[chc*4+3];
    const float cbb = conv_b[chc];

    const _Float16* pb = projh + (size_t)b * kL * kLdp;
    const int colx = 2048 + chx;
    const int colc = 2048 + chc;     // = 4096 + l

    float xq0=0.f, xq1=0.f, xq2=0.f, cq0=0.f, cq1=0.f, cq2=0.f;
    if (c > 0) {
        xq0 = (float)pb[(size_t)(t0-3)*kLdp + colx];
        xq1 = (float)pb[(size_t)(t0-2)*kLdp + colx];
        xq2 = (float)pb[(size_t)(t0-1)*kLdp + colx];
        cq0 = (float)pb[(size_t)(t0-3)*kLdp + colc];
        cq1 = (float)pb[(size_t)(t0-2)*kLdp + colc];
        cq2 = (float)pb[(size_t)(t0-1)*kLdp + colc];
    }

    float hs[kN];
    const float* cs = cstate + (size_t)blk * (kP * kN) + l * kN;
    #pragma unroll
    for (int n = 0; n < kN; ++n) hs[n] = cs[n];
    const float Dh = D_param[h];
    const float* dtp = dtv + (size_t)bh * kL;
    const float* dAp = dAv + (size_t)bh * kL;
    float* yo = ypre + (size_t)b * kL * kD + h * kP + l;

    float xv = (float)pb[(size_t)t0 * kLdp + colx];
    float cv = (float)pb[(size_t)t0 * kLdp + colc];
    float dt = dtp[t0], dA = dAp[t0];

    #pragma unroll 1
    for (int t = t0; t < t0 + kLC; ++t) {
        float xn = 0.f, cn2 = 0.f, dtn = 0.f, dAn = 0.f;
        if (t + 1 < t0 + kLC) {
            const size_t ro2 = (size_t)(t + 1) * kLdp;
            xn = (float)pb[ro2 + colx];
            cn2 = (float)pb[ro2 + colc];
            dtn = dtp[t + 1]; dAn = dAp[t + 1];
        }
        float sx = silu_f(xbb + xw0*xq0 + xw1*xq1 + xw2*xq2 + xw3*xv);
        float sc = silu_f(cbb + cw0*cq0 + cw1*cq1 + cw2*cq2 + cw3*cv);
        xq0=xq1; xq1=xq2; xq2=xv;
        cq0=cq1; cq1=cq2; cq2=cv;
        float dtx = dt * sx;
        float y0 = Dh * sx, y1 = 0.f;
        #pragma unroll
        for (int n = 0; n < kN; ++n) {
            float bn = lane_bcast(sc, n);
            float cn = lane_bcast(sc, n + 32);
            hs[n] = fmaf(dA, hs[n], dtx * bn);
            if (n & 1) y1 = fmaf(hs[n], cn, y1);
            else       y0 = fmaf(hs[n], cn, y0);
        }
        yo[(size_t)t * kD] = y0 + y1;
        xv = xn; cv = cn2; dt = dtn; dA = dAn;
    }
}

// ---------------- gated RMSNorm -> f16 ----------------
__global__ __launch_bounds__(256) void gated_norm_kernel(
    const float* __restrict__ ypre, const _Float16* __restrict__ projh,
    const float* __restrict__ norm_w, _Float16* __restrict__ yh)
{
    const int row = blockIdx.x;
    const int tid = threadIdx.x;
    const float* yr = ypre + (size_t)row * kD;
    const _Float16* gr = projh + (size_t)row * kLdp;   // gate = cols [0,2048)
    float v[8];
    float ss = 0.f;
    #pragma unroll
    for (int u = 0; u < 8; ++u) {
        int col = tid + u * 256;
        float g = (float)gr[col];
        float t = yr[col] * (g / (1.f + __expf(-g)));
        v[u] = t;
        ss = fmaf(t, t, ss);
    }
    #pragma unroll
    for (int off = 32; off > 0; off >>= 1) ss += __shfl_xor(ss, off, 64);
    __shared__ float red[4];
    if ((tid & 63) == 0) red[tid >> 6] = ss;
    __syncthreads();
    float tot = (red[0] + red[1]) + (red[2] + red[3]);
    float scl = rsqrtf(tot * (1.f / (float)kD) + 1e-6f);
    #pragma unroll
    for (int u = 0; u < 8; ++u) {
        int col = tid + u * 256;
        yh[(size_t)row * kD + col] = (_Float16)(v[u] * scl * norm_w[col]);
    }
}

// ---------------- launcher ----------------
extern "C" void kernel_launch(void* const* d_in, const int* in_sizes, int n_in,
                              void* d_out, int out_size, void* d_ws, size_t ws_size,
                              hipStream_t stream)
{
    (void)in_sizes; (void)n_in; (void)out_size; (void)ws_size;
    const float* x       = (const float*)d_in[0];
    const float* W_in    = (const float*)d_in[1];
    const float* b_in    = (const float*)d_in[2];
    const float* conv_w  = (const float*)d_in[3];
    const float* conv_b  = (const float*)d_in[4];
    const float* A_log   = (const float*)d_in[5];
    const float* dt_bias = (const float*)d_in[6];
    const float* D_param = (const float*)d_in[7];
    const float* norm_w  = (const float*)d_in[8];
    const float* W_out   = (const float*)d_in[9];
    float* out = (float*)d_out;

    char* p = (char*)d_ws;
    _Float16* projh = (_Float16*)p; p += (size_t)kM * kLdp * 2;     // 69.2 MB
    _Float16* xh    = (_Float16*)p; p += (size_t)kM * kD * 2;       // 32 MiB (xh -> cstate -> yh)
    _Float16* Wt    = (_Float16*)p; p += (size_t)kLdp * kK * 2;     // 17.3 MB
    _Float16* Wot   = (_Float16*)p; p += (size_t)kD * kK * 2;       //  8.4 MB
    float* dtv      = (float*)p;    p += (size_t)kB * kH * kL * 4;  //  1.0 MB
    float* dAv      = (float*)p;    p += (size_t)kB * kH * kL * 4;  //  1.0 MB
    float* Pch      = (float*)p;    p += (size_t)kB * kH * kNC * 4;
    // buffer lifetimes on the 32 MiB region: xh [cast..GEMM1b] ->
    // cstate [pass1..pass3] -> yh [gated_norm..GEMM2]; all disjoint.
    float* cstate = (float*)xh;
    _Float16* yh  = xh;
    float* ypre = out;            // d_out used as fp32 scratch, overwritten by GEMM2

    // 1. cast x -> f16
    cast_f16_kernel<<<(kM * kD) / (256 * 8), 256, 0, stream>>>(x, xh);
    // 2-3. transpose+cast weights to N x K (pad W_in cols 4192->4224 with zeros)
    transpose_cast_kernel<<<dim3(kLdp / 32, kK / 32), 256, 0, stream>>>(W_in, Wt, kK, kProjW);
    transpose_cast_kernel<<<dim3(kD / 32, kK / 32), 256, 0, stream>>>(W_out, Wot, kK, kD);
    // 4. GEMM1a: proj cols [0,4096) — 512 blocks = exactly 2 resident rounds
    gemm256_kernel<true><<<512, 512, 0, stream>>>(
        xh, Wt, b_in, kProjW, (void*)projh, kK, kLdp, 4096, 16);
    // 5. GEMM1b: proj cols [4096,4224) (B/C/dt), dt/dA fused into epilogue
    gemm_tail_kernel<<<kM / 32, 256, 0, stream>>>(
        xh, Wt + (size_t)4096 * kK, b_in + 4096, projh, A_log, dt_bias, dtv, dAv);
    // 6-8. chunked scan (conv fused), kLC=64 -> 4096 blocks (4 waves/SIMD)
    scan_pass1_kernel<<<kB * kH * kNC, 64, 0, stream>>>(projh, conv_w, conv_b, dtv, dAv, cstate, Pch);
    scan_pass2_kernel<<<kB * kH, 256, 0, stream>>>(cstate, Pch);
    scan_pass3_kernel<<<kB * kH * kNC, 64, 0, stream>>>(projh, conv_w, conv_b, dtv, dAv, cstate, D_param, ypre);
    // 9. gated RMSNorm -> f16
    gated_norm_kernel<<<kM, 256, 0, stream>>>(ypre, projh, norm_w, yh);
    // 10. GEMM2: out = y @ W_out (256 blocks = exactly 1 resident round)
    gemm256_kernel<false><<<256, 512, 0, stream>>>(
        yh, Wot, nullptr, 0, (void*)out, kK, kD, kD, 8);
}